// Round 4
// baseline (423.539 us; speedup 1.0000x reference)
//
#include <hip/hip_runtime.h>
#include <cmath>

#define BB 8
#define CC 256
#define CQ 64
#define NN 4096
constexpr float INV_N = 1.0f / 4096.0f;

typedef __attribute__((ext_vector_type(8))) short short8;
typedef __attribute__((ext_vector_type(4))) short short4v;
typedef __attribute__((ext_vector_type(4))) float float4v;

__device__ __forceinline__ short f2bf(float f) {
  union { float f; unsigned u; } x; x.f = f;
  unsigned r = x.u + 0x7fffu + ((x.u >> 16) & 1u);
  return (short)(r >> 16);
}

// ---------------------------------------------------------------------------
// prep: blocks 0..63 -> Wv' = Wg@Wv (fp32 accum, bf16 out), 32x32 tiles;
//       block 64 -> convert wq,wk to bf16; block 65 -> bv' = Wg@bv (fp32).
// ---------------------------------------------------------------------------
__global__ __launch_bounds__(256) void prep_kernel(
    const float* __restrict__ wq, const float* __restrict__ wk,
    const float* __restrict__ wv, const float* __restrict__ wg,
    const float* __restrict__ bv,
    short* __restrict__ wqbf, short* __restrict__ wkbf,
    short* __restrict__ wvpbf, float* __restrict__ bvp) {
  const int bx = blockIdx.x;
  const int tid = threadIdx.x;
  if (bx < 64) {
    const int o0 = (bx >> 3) * 32, c0 = (bx & 7) * 32;
    const int cc = tid & 31, oo = tid >> 5;  // oo 0..7
    float acc[4] = {0.f, 0.f, 0.f, 0.f};
    for (int u = 0; u < 256; ++u) {
      const float xv = wv[(size_t)u * 256 + c0 + cc];
#pragma unroll
      for (int i = 0; i < 4; ++i)
        acc[i] += wg[(size_t)(o0 + oo * 4 + i) * 256 + u] * xv;
    }
#pragma unroll
    for (int i = 0; i < 4; ++i)
      wvpbf[(size_t)(o0 + oo * 4 + i) * 256 + c0 + cc] = f2bf(acc[i]);
  } else if (bx == 64) {
#pragma unroll 4
    for (int t = 0; t < 16; ++t) {
      const int idx = (t * 256 + tid) * 4;
      const float4 a = *reinterpret_cast<const float4*>(&wq[idx]);
      short4v p; p.x = f2bf(a.x); p.y = f2bf(a.y); p.z = f2bf(a.z); p.w = f2bf(a.w);
      *reinterpret_cast<short4v*>(&wqbf[idx]) = p;
      const float4 b4 = *reinterpret_cast<const float4*>(&wk[idx]);
      short4v q4; q4.x = f2bf(b4.x); q4.y = f2bf(b4.y); q4.z = f2bf(b4.z); q4.w = f2bf(b4.w);
      *reinterpret_cast<short4v*>(&wkbf[idx]) = q4;
    }
  } else {
    float acc = 0.f;
    for (int u = 0; u < 256; ++u) acc += wg[(size_t)tid * 256 + u] * bv[u];
    bvp[tid] = acc;
  }
}

// ---------------------------------------------------------------------------
// qkv: n-tile 32, grid (B, NN/32). Stages x transposed into LDS bf16 with
// XOR-swizzled 4-dword chunks (conflict-free writes & b128 reads), then
// 6 chunks of 64 output channels (q | k | vtilde0..3) via MFMA with
// pre-converted bf16 weights as A-frags (global, L2-resident, prefetched).
// ---------------------------------------------------------------------------
__global__ __launch_bounds__(256, 4) void qkv_kernel(
    const float* __restrict__ X,
    const short* __restrict__ wqbf, const short* __restrict__ wkbf,
    const short* __restrict__ wvpbf,
    const float* __restrict__ bq, const float* __restrict__ bk,
    const float* __restrict__ bvp,
    short* __restrict__ qt, short* __restrict__ kt, short* __restrict__ vt) {
  __shared__ short smem[8448 + 2560];
  short* xt = smem;              // [32 n][264 c] bf16, XOR-swizzled chunks
  short* Os = smem + 8448;       // [64 o][40 n] vtilde staging

  const int tid = threadIdx.x;
  const int wid = tid >> 6;
  const int lane = tid & 63, quad = lane >> 4, l16 = lane & 15;
  const int b = blockIdx.x, n0 = blockIdx.y * 32;

  // ---- stage x -> xt[n][c] bf16 (swizzled transpose) ----
#pragma unroll
  for (int p = 0; p < 8; ++p) {
    const int idx = p * 256 + tid;
    const int c = idx >> 3;           // 0..255
    const int n4 = (idx & 7) * 4;     // 0,4,...,28
    const float4 x4 = *reinterpret_cast<const float4*>(
        &X[((size_t)b * CC + c) * NN + n0 + n4]);
    const int sw = (n4 >> 2) & 7;
    const int chp = (c >> 3) ^ sw;
    const int cols = chp * 8 + (c & 7);
    xt[(n4 + 0) * 264 + cols] = f2bf(x4.x);
    xt[(n4 + 1) * 264 + cols] = f2bf(x4.y);
    xt[(n4 + 2) * 264 + cols] = f2bf(x4.z);
    xt[(n4 + 3) * 264 + cols] = f2bf(x4.w);
  }
  __syncthreads();

  const short* Wsrc[6] = {wqbf, wkbf, wvpbf, wvpbf + 64 * 256,
                          wvpbf + 128 * 256, wvpbf + 192 * 256};
  const int arow = wid * 16 + l16;

  short8 curA[8];
#pragma unroll
  for (int kk = 0; kk < 8; ++kk)
    curA[kk] = *reinterpret_cast<const short8*>(
        &Wsrc[0][(size_t)arow * 256 + kk * 32 + quad * 8]);

#pragma unroll
  for (int ch = 0; ch < 6; ++ch) {
    short8 nxtA[8];
    if (ch < 5) {
#pragma unroll
      for (int kk = 0; kk < 8; ++kk)
        nxtA[kk] = *reinterpret_cast<const short8*>(
            &Wsrc[ch + 1][(size_t)arow * 256 + kk * 32 + quad * 8]);
    }

    float4v acc2[2];
    acc2[0] = float4v{0.f, 0.f, 0.f, 0.f};
    acc2[1] = float4v{0.f, 0.f, 0.f, 0.f};
#pragma unroll
    for (int kk = 0; kk < 8; ++kk) {
#pragma unroll
      for (int tm = 0; tm < 2; ++tm) {
        const int row = tm * 16 + l16;
        const int swr = (row >> 2) & 7;
        const short8 bfrag = *reinterpret_cast<const short8*>(
            &xt[row * 264 + ((kk * 4 + quad) ^ swr) * 8]);
        acc2[tm] = __builtin_amdgcn_mfma_f32_16x16x32_bf16(curA[kk], bfrag,
                                                           acc2[tm], 0, 0, 0);
      }
    }

    if (ch < 2) {
      const float* bias = (ch == 0) ? bq : bk;
      const float4v bv4 = *reinterpret_cast<const float4v*>(
          &bias[wid * 16 + quad * 4]);
      short* dst = (ch == 0) ? qt : kt;
#pragma unroll
      for (int tm = 0; tm < 2; ++tm) {
        short4v pk;
#pragma unroll
        for (int r = 0; r < 4; ++r) pk[r] = f2bf(acc2[tm][r] + bv4[r]);
        *reinterpret_cast<short4v*>(
            &dst[((size_t)b * NN + n0 + tm * 16 + l16) * 64 + wid * 16 +
                 quad * 4]) = pk;
      }
    } else {
      const float4v bv4 = *reinterpret_cast<const float4v*>(
          &bvp[(ch - 2) * 64 + wid * 16 + quad * 4]);
      __syncthreads();  // prior chunk's Os reads done
#pragma unroll
      for (int tm = 0; tm < 2; ++tm)
#pragma unroll
        for (int r = 0; r < 4; ++r)
          Os[(wid * 16 + quad * 4 + r) * 40 + tm * 16 + l16] =
              f2bf(acc2[tm][r] + bv4[r]);
      __syncthreads();
      const int o = tid >> 2, ng = (tid & 3) * 8;
      const short8 s0 = *reinterpret_cast<const short8*>(&Os[o * 40 + ng]);
      *reinterpret_cast<short8*>(
          &vt[((size_t)b * CC + (ch - 2) * 64 + o) * NN + n0 + ng]) = s0;
    }
#pragma unroll
    for (int kk = 0; kk < 8; ++kk) curA[kk] = nxtA[kk];
  }
}

// ---------------------------------------------------------------------------
// attn v3: m-tile 32, grid (B, NN/32) [batch-major for XCD L2 affinity].
// k-frags in regs; q A-frags from global (prefetched); vtilde A-frags from
// global; Es double-buffered, ONE barrier/iter; epilogue = acc + bg only
// (gamma folded into vtilde by prep).
// ---------------------------------------------------------------------------
__global__ __launch_bounds__(256, 4) void attn_kernel(
    const short* __restrict__ qt, const short* __restrict__ kt,
    const short* __restrict__ vt, const float* __restrict__ bg,
    float* __restrict__ out) {
  __shared__ short smem[4608];
  short* Es0 = smem;              // [32 m][72 n]
  short* Es1 = smem + 2304;

  const int tid = threadIdx.x;
  const int wid = tid >> 6;
  const int lane = tid & 63, quad = lane >> 4, l16 = lane & 15;
  const int b = blockIdx.x, m0 = blockIdx.y * 32;

  short8 bkf[2][2];
#pragma unroll
  for (int tm = 0; tm < 2; ++tm)
#pragma unroll
    for (int kk = 0; kk < 2; ++kk)
      bkf[tm][kk] = *reinterpret_cast<const short8*>(
          &kt[((size_t)b * NN + m0 + tm * 16 + l16) * 64 + kk * 32 + quad * 8]);

  const short* qrow = &qt[((size_t)b * NN + wid * 16 + l16) * 64 + quad * 8];
  const short* vrow[4];
#pragma unroll
  for (int tc = 0; tc < 4; ++tc)
    vrow[tc] = &vt[((size_t)b * CC + wid * 64 + tc * 16 + l16) * NN + quad * 8];

  float4v acc[4][2];
#pragma unroll
  for (int i = 0; i < 4; ++i)
#pragma unroll
    for (int j = 0; j < 2; ++j) acc[i][j] = float4v{0.f, 0.f, 0.f, 0.f};

  short8 aq0 = *reinterpret_cast<const short8*>(qrow);
  short8 aq1 = *reinterpret_cast<const short8*>(qrow + 32);

  for (int it = 0; it < 64; ++it) {
    const int nb = it * 64;
    short* Esw = (it & 1) ? Es1 : Es0;

    // vtilde fragments for this iter — issued early, used after barrier
    short8 av[4][2];
#pragma unroll
    for (int tc = 0; tc < 4; ++tc) {
      av[tc][0] = *reinterpret_cast<const short8*>(vrow[tc] + nb);
      av[tc][1] = *reinterpret_cast<const short8*>(vrow[tc] + nb + 32);
    }

    // S = q^T k : wave owns n-rows [wid*16,+16), both 16-m tiles
    float4v s[2];
#pragma unroll
    for (int tm2 = 0; tm2 < 2; ++tm2) {
      float4v t = {0.f, 0.f, 0.f, 0.f};
      t = __builtin_amdgcn_mfma_f32_16x16x32_bf16(aq0, bkf[tm2][0], t, 0, 0, 0);
      t = __builtin_amdgcn_mfma_f32_16x16x32_bf16(aq1, bkf[tm2][1], t, 0, 0, 0);
      s[tm2] = t;
    }

    // prefetch next iter's q (last-iter over-read lands in kt region — safe)
    const short8 aq0n =
        *reinterpret_cast<const short8*>(qrow + (size_t)(it + 1) * 64 * 64);
    const short8 aq1n =
        *reinterpret_cast<const short8*>(qrow + (size_t)(it + 1) * 64 * 64 + 32);

    // elu/N -> Es  (C layout: m = tm2*16+l16, n = wid*16+quad*4+r)
#pragma unroll
    for (int tm2 = 0; tm2 < 2; ++tm2) {
      short4v pk;
#pragma unroll
      for (int r = 0; r < 4; ++r) {
        float sv = s[tm2][r];
        sv = (sv > 0.f) ? sv : (__expf(sv) - 1.f);
        pk[r] = f2bf(sv * INV_N);
      }
      *reinterpret_cast<short4v*>(
          &Esw[(tm2 * 16 + l16) * 72 + wid * 16 + quad * 4]) = pk;
    }
    __syncthreads();

    // PV: acc[c-tile][m-tile] += vtilde @ E
#pragma unroll
    for (int tm = 0; tm < 2; ++tm) {
      const short8 be0 = *reinterpret_cast<const short8*>(
          &Esw[(tm * 16 + l16) * 72 + quad * 8]);
      const short8 be1 = *reinterpret_cast<const short8*>(
          &Esw[(tm * 16 + l16) * 72 + 32 + quad * 8]);
#pragma unroll
      for (int tc = 0; tc < 4; ++tc) {
        acc[tc][tm] = __builtin_amdgcn_mfma_f32_16x16x32_bf16(
            av[tc][0], be0, acc[tc][tm], 0, 0, 0);
        acc[tc][tm] = __builtin_amdgcn_mfma_f32_16x16x32_bf16(
            av[tc][1], be1, acc[tc][tm], 0, 0, 0);
      }
    }
    aq0 = aq0n; aq1 = aq1n;
  }

  // ---- epilogue: + bg only (gamma already folded into vtilde) ----
#pragma unroll
  for (int tc = 0; tc < 4; ++tc) {
    const float4v bg4 = *reinterpret_cast<const float4v*>(
        &bg[wid * 64 + tc * 16 + quad * 4]);
#pragma unroll
    for (int r = 0; r < 4; ++r) {
      const int c = wid * 64 + tc * 16 + quad * 4 + r;
#pragma unroll
      for (int tm = 0; tm < 2; ++tm) {
        out[((size_t)b * CC + c) * NN + m0 + tm * 16 + l16] =
            acc[tc][tm][r] + bg4[r];
      }
    }
  }
}

// ---------------------------------------------------------------------------
extern "C" void kernel_launch(void* const* d_in, const int* in_sizes, int n_in,
                              void* d_out, int out_size, void* d_ws,
                              size_t ws_size, hipStream_t stream) {
  const float* x  = (const float*)d_in[0];
  const float* wq = (const float*)d_in[1];
  const float* bq = (const float*)d_in[2];
  const float* wk = (const float*)d_in[3];
  const float* bk = (const float*)d_in[4];
  const float* wv = (const float*)d_in[5];
  const float* bv = (const float*)d_in[6];
  const float* wg = (const float*)d_in[7];
  const float* bg = (const float*)d_in[8];
  float* out = (float*)d_out;

  short* qt    = (short*)d_ws;                       // [B][N][64]   4 MB
  short* kt    = qt + (size_t)BB * NN * CQ;          // [B][N][64]   4 MB
  short* vt    = kt + (size_t)BB * NN * CQ;          // [B][C][N]   16 MB
  short* wqbf  = vt + (size_t)BB * CC * NN;          // 32 KB
  short* wkbf  = wqbf + (size_t)CQ * CC;             // 32 KB
  short* wvpbf = wkbf + (size_t)CQ * CC;             // 128 KB
  float* bvp   = (float*)(wvpbf + (size_t)CC * CC);  // 1 KB

  prep_kernel<<<dim3(66), 256, 0, stream>>>(wq, wk, wv, wg, bv,
                                            wqbf, wkbf, wvpbf, bvp);
  qkv_kernel<<<dim3(BB, NN / 32), 256, 0, stream>>>(
      x, wqbf, wkbf, wvpbf, bq, bk, bvp, qt, kt, vt);
  attn_kernel<<<dim3(BB, NN / 32), 256, 0, stream>>>(qt, kt, vt, bg, out);
}

// Round 5
// 315.653 us; speedup vs baseline: 1.3418x; 1.3418x over previous
//
#include <hip/hip_runtime.h>
#include <cmath>

#define BB 8
#define CC 256
#define CQ 64
#define NN 4096
constexpr float INV_N = 1.0f / 4096.0f;

typedef __attribute__((ext_vector_type(8))) short short8;
typedef __attribute__((ext_vector_type(4))) short short4v;
typedef __attribute__((ext_vector_type(4))) float float4v;

__device__ __forceinline__ short f2bf(float f) {
  union { float f; unsigned u; } x; x.f = f;
  unsigned r = x.u + 0x7fffu + ((x.u >> 16) & 1u);
  return (short)(r >> 16);
}

// ---------------------------------------------------------------------------
// prep: blocks 0..63 -> Wv' = Wg@Wv (fp32 accum, bf16 out), 32x32 tiles;
//       block 64 -> convert wq,wk to bf16; block 65 -> bv' = Wg@bv (fp32).
// ---------------------------------------------------------------------------
__global__ __launch_bounds__(256) void prep_kernel(
    const float* __restrict__ wq, const float* __restrict__ wk,
    const float* __restrict__ wv, const float* __restrict__ wg,
    const float* __restrict__ bv,
    short* __restrict__ wqbf, short* __restrict__ wkbf,
    short* __restrict__ wvpbf, float* __restrict__ bvp) {
  const int bx = blockIdx.x;
  const int tid = threadIdx.x;
  if (bx < 64) {
    const int o0 = (bx >> 3) * 32, c0 = (bx & 7) * 32;
    const int cc = tid & 31, oo = tid >> 5;  // oo 0..7
    float acc[4] = {0.f, 0.f, 0.f, 0.f};
    for (int u = 0; u < 256; ++u) {
      const float xv = wv[(size_t)u * 256 + c0 + cc];
#pragma unroll
      for (int i = 0; i < 4; ++i)
        acc[i] += wg[(size_t)(o0 + oo * 4 + i) * 256 + u] * xv;
    }
#pragma unroll
    for (int i = 0; i < 4; ++i)
      wvpbf[(size_t)(o0 + oo * 4 + i) * 256 + c0 + cc] = f2bf(acc[i]);
  } else if (bx == 64) {
#pragma unroll 4
    for (int t = 0; t < 16; ++t) {
      const int idx = (t * 256 + tid) * 4;
      const float4 a = *reinterpret_cast<const float4*>(&wq[idx]);
      short4v p; p.x = f2bf(a.x); p.y = f2bf(a.y); p.z = f2bf(a.z); p.w = f2bf(a.w);
      *reinterpret_cast<short4v*>(&wqbf[idx]) = p;
      const float4 b4 = *reinterpret_cast<const float4*>(&wk[idx]);
      short4v q4; q4.x = f2bf(b4.x); q4.y = f2bf(b4.y); q4.z = f2bf(b4.z); q4.w = f2bf(b4.w);
      *reinterpret_cast<short4v*>(&wkbf[idx]) = q4;
    }
  } else {
    float acc = 0.f;
    for (int u = 0; u < 256; ++u) acc += wg[(size_t)tid * 256 + u] * bv[u];
    bvp[tid] = acc;
  }
}

// ---------------------------------------------------------------------------
// qkv: n-tile 32, grid (B, NN/32). Transposed x staged in LDS bf16 with
// XOR-swizzled chunks; b64 packed stores (conflict-free). 6 chunks of 64
// output channels (q | k | vtilde0..3) via MFMA; weights loaded per-chunk
// from L2 (no prefetch regs -> fits 4 blocks/CU).
// ---------------------------------------------------------------------------
__global__ __launch_bounds__(256, 4) void qkv_kernel(
    const float* __restrict__ X,
    const short* __restrict__ wqbf, const short* __restrict__ wkbf,
    const short* __restrict__ wvpbf,
    const float* __restrict__ bq, const float* __restrict__ bk,
    const float* __restrict__ bvp,
    short* __restrict__ qt, short* __restrict__ kt, short* __restrict__ vt) {
  __shared__ short smem[8448 + 2560];
  short* xt = smem;              // [32 n][264 c] bf16, XOR-swizzled chunks
  short* Os = smem + 8448;       // [64 o][40 n] vtilde staging

  const int tid = threadIdx.x;
  const int wid = tid >> 6;
  const int lane = tid & 63, quad = lane >> 4, l16 = lane & 15;
  const int b = blockIdx.x, n0 = blockIdx.y * 32;

  // ---- stage x -> xt[n][c] bf16, packed b64 writes (4 channels/write) ----
#pragma unroll
  for (int p = 0; p < 2; ++p) {
    const int idx = p * 256 + tid;
    const int cg = idx >> 3;          // 4-channel group 0..63
    const int ng = idx & 7;           // 4-row group 0..7
    float4 xr[4];
#pragma unroll
    for (int j = 0; j < 4; ++j)
      xr[j] = *reinterpret_cast<const float4*>(
          &X[((size_t)b * CC + cg * 4 + j) * NN + n0 + ng * 4]);
    const int colbase = (((cg >> 1) ^ ng) * 8 + (cg & 1) * 4);
#pragma unroll
    for (int r = 0; r < 4; ++r) {
      short4v pk;
      pk.x = f2bf((&xr[0].x)[r]); pk.y = f2bf((&xr[1].x)[r]);
      pk.z = f2bf((&xr[2].x)[r]); pk.w = f2bf((&xr[3].x)[r]);
      *reinterpret_cast<short4v*>(&xt[(ng * 4 + r) * 264 + colbase]) = pk;
    }
  }
  __syncthreads();

  const short* Wsrc[6] = {wqbf, wkbf, wvpbf, wvpbf + 64 * 256,
                          wvpbf + 128 * 256, wvpbf + 192 * 256};
  const int arow = wid * 16 + l16;

#pragma unroll
  for (int ch = 0; ch < 6; ++ch) {
    float4v acc2[2];
    acc2[0] = float4v{0.f, 0.f, 0.f, 0.f};
    acc2[1] = float4v{0.f, 0.f, 0.f, 0.f};
#pragma unroll
    for (int kk = 0; kk < 8; ++kk) {
      const short8 a = *reinterpret_cast<const short8*>(
          &Wsrc[ch][(size_t)arow * 256 + kk * 32 + quad * 8]);
#pragma unroll
      for (int tm = 0; tm < 2; ++tm) {
        const int row = tm * 16 + l16;
        const int swr = (row >> 2) & 7;
        const short8 bfrag = *reinterpret_cast<const short8*>(
            &xt[row * 264 + ((kk * 4 + quad) ^ swr) * 8]);
        acc2[tm] = __builtin_amdgcn_mfma_f32_16x16x32_bf16(a, bfrag,
                                                           acc2[tm], 0, 0, 0);
      }
    }

    if (ch < 2) {
      const float* bias = (ch == 0) ? bq : bk;
      const float4v bv4 = *reinterpret_cast<const float4v*>(
          &bias[wid * 16 + quad * 4]);
      short* dst = (ch == 0) ? qt : kt;
#pragma unroll
      for (int tm = 0; tm < 2; ++tm) {
        short4v pk;
#pragma unroll
        for (int r = 0; r < 4; ++r) pk[r] = f2bf(acc2[tm][r] + bv4[r]);
        *reinterpret_cast<short4v*>(
            &dst[((size_t)b * NN + n0 + tm * 16 + l16) * 64 + wid * 16 +
                 quad * 4]) = pk;
      }
    } else {
      const float4v bv4 = *reinterpret_cast<const float4v*>(
          &bvp[(ch - 2) * 64 + wid * 16 + quad * 4]);
      __syncthreads();  // prior chunk's Os reads done
#pragma unroll
      for (int tm = 0; tm < 2; ++tm)
#pragma unroll
        for (int r = 0; r < 4; ++r)
          Os[(wid * 16 + quad * 4 + r) * 40 + tm * 16 + l16] =
              f2bf(acc2[tm][r] + bv4[r]);
      __syncthreads();
      const int o = tid >> 2, ng = (tid & 3) * 8;
      const short8 s0 = *reinterpret_cast<const short8*>(&Os[o * 40 + ng]);
      *reinterpret_cast<short8*>(
          &vt[((size_t)b * CC + (ch - 2) * 64 + o) * NN + n0 + ng]) = s0;
    }
  }
}

// ---------------------------------------------------------------------------
// attn r5: m=64/block, c-split 2 (block owns 128 channels), grid
// (2 chalf, 64 m, 8 b) = 1024 blocks at 4 blocks/CU.
// Pipelined: S(it+1) || PV(it), ONE barrier/iter. k frags resident; v/q
// loads issued at iter bottom into same regs (cover = next S + barrier).
// Gamma folded into vtilde (prep); epilogue adds bg only.
// ---------------------------------------------------------------------------
__global__ __launch_bounds__(256, 4) void attn_kernel(
    const short* __restrict__ qt, const short* __restrict__ kt,
    const short* __restrict__ vt, const float* __restrict__ bg,
    float* __restrict__ out) {
  __shared__ short Es[2][64 * 72];   // [m][n], 18.4 KB total

  const int tid = threadIdx.x;
  const int wid = tid >> 6;
  const int lane = tid & 63, quad = lane >> 4, l16 = lane & 15;
  const int chalf = blockIdx.x;
  const int m0 = blockIdx.y * 64;
  const int b = blockIdx.z;

  // k fragments: resident (S B-operand), 4 m-tiles x K64
  short8 kf[4][2];
#pragma unroll
  for (int tm = 0; tm < 4; ++tm)
#pragma unroll
    for (int kk = 0; kk < 2; ++kk)
      kf[tm][kk] = *reinterpret_cast<const short8*>(
          &kt[((size_t)b * NN + m0 + tm * 16 + l16) * 64 + kk * 32 + quad * 8]);

  // q A-frag row base (wave's 16 n-rows of each 64-n window)
  const short* qrow = &qt[((size_t)b * NN + wid * 16 + l16) * 64 + quad * 8];
  // v rows: wave owns channels chalf*128 + wid*32 + {0,16} + l16
  const short* vrow[2];
#pragma unroll
  for (int tc = 0; tc < 2; ++tc)
    vrow[tc] = &vt[((size_t)b * CC + chalf * 128 + wid * 32 + tc * 16 + l16) *
                       NN + quad * 8];

  float4v acc[2][4];
#pragma unroll
  for (int i = 0; i < 2; ++i)
#pragma unroll
    for (int j = 0; j < 4; ++j) acc[i][j] = float4v{0.f, 0.f, 0.f, 0.f};

  // ---- prologue: S(0) -> Es[0]; load av(0); load aq <- q(1) ----
  short8 aq0 = *reinterpret_cast<const short8*>(qrow);
  short8 aq1 = *reinterpret_cast<const short8*>(qrow + 32);
  {
    float4v s[4];
#pragma unroll
    for (int tm = 0; tm < 4; ++tm) {
      float4v t = {0.f, 0.f, 0.f, 0.f};
      t = __builtin_amdgcn_mfma_f32_16x16x32_bf16(aq0, kf[tm][0], t, 0, 0, 0);
      t = __builtin_amdgcn_mfma_f32_16x16x32_bf16(aq1, kf[tm][1], t, 0, 0, 0);
      s[tm] = t;
    }
#pragma unroll
    for (int tm = 0; tm < 4; ++tm) {
      short4v pk;
#pragma unroll
      for (int r = 0; r < 4; ++r) {
        float sv = s[tm][r];
        sv = (sv > 0.f) ? sv : (__expf(sv) - 1.f);
        pk[r] = f2bf(sv * INV_N);
      }
      *reinterpret_cast<short4v*>(
          &Es[0][(tm * 16 + l16) * 72 + wid * 16 + quad * 4]) = pk;
    }
  }
  short8 av[2][2];
#pragma unroll
  for (int tc = 0; tc < 2; ++tc) {
    av[tc][0] = *reinterpret_cast<const short8*>(vrow[tc]);
    av[tc][1] = *reinterpret_cast<const short8*>(vrow[tc] + 32);
  }
  aq0 = *reinterpret_cast<const short8*>(qrow + 64 * 64);
  aq1 = *reinterpret_cast<const short8*>(qrow + 64 * 64 + 32);
  __syncthreads();

  for (int it = 0; it < 64; ++it) {
    const int rb = it & 1, wb = rb ^ 1;

    // ---- S(it+1) with aq = q(it+1); garbage at it=63 (never read) ----
    float4v s[4];
#pragma unroll
    for (int tm = 0; tm < 4; ++tm) {
      float4v t = {0.f, 0.f, 0.f, 0.f};
      t = __builtin_amdgcn_mfma_f32_16x16x32_bf16(aq0, kf[tm][0], t, 0, 0, 0);
      t = __builtin_amdgcn_mfma_f32_16x16x32_bf16(aq1, kf[tm][1], t, 0, 0, 0);
      s[tm] = t;
    }
    // elu/N -> Es[wb]
#pragma unroll
    for (int tm = 0; tm < 4; ++tm) {
      short4v pk;
#pragma unroll
      for (int r = 0; r < 4; ++r) {
        float sv = s[tm][r];
        sv = (sv > 0.f) ? sv : (__expf(sv) - 1.f);
        pk[r] = f2bf(sv * INV_N);
      }
      *reinterpret_cast<short4v*>(
          &Es[wb][(tm * 16 + l16) * 72 + wid * 16 + quad * 4]) = pk;
    }

    // ---- PV(it): read Es[rb], MFMA with av = v(it) ----
#pragma unroll
    for (int tm = 0; tm < 4; ++tm) {
      const short8 be0 = *reinterpret_cast<const short8*>(
          &Es[rb][(tm * 16 + l16) * 72 + quad * 8]);
      const short8 be1 = *reinterpret_cast<const short8*>(
          &Es[rb][(tm * 16 + l16) * 72 + 32 + quad * 8]);
#pragma unroll
      for (int tc = 0; tc < 2; ++tc) {
        acc[tc][tm] = __builtin_amdgcn_mfma_f32_16x16x32_bf16(
            av[tc][0], be0, acc[tc][tm], 0, 0, 0);
        acc[tc][tm] = __builtin_amdgcn_mfma_f32_16x16x32_bf16(
            av[tc][1], be1, acc[tc][tm], 0, 0, 0);
      }
    }

    // ---- loads for next iter (land during next S + barrier) ----
    {
      const size_t nb = (size_t)(it + 1) * 64;
#pragma unroll
      for (int tc = 0; tc < 2; ++tc) {
        av[tc][0] = *reinterpret_cast<const short8*>(vrow[tc] + nb);
        av[tc][1] = *reinterpret_cast<const short8*>(vrow[tc] + nb + 32);
      }
      aq0 = *reinterpret_cast<const short8*>(qrow + (size_t)(it + 2) * 64 * 64);
      aq1 = *reinterpret_cast<const short8*>(qrow + (size_t)(it + 2) * 64 * 64 + 32);
    }
    __syncthreads();
  }

  // ---- epilogue: + bg (gamma folded into vtilde) ----
#pragma unroll
  for (int tc = 0; tc < 2; ++tc) {
#pragma unroll
    for (int r = 0; r < 4; ++r) {
      const int c = chalf * 128 + wid * 32 + tc * 16 + quad * 4 + r;
      const float bgv = bg[c];
#pragma unroll
      for (int tm = 0; tm < 4; ++tm) {
        out[((size_t)b * CC + c) * NN + m0 + tm * 16 + l16] =
            acc[tc][tm][r] + bgv;
      }
    }
  }
}

// ---------------------------------------------------------------------------
extern "C" void kernel_launch(void* const* d_in, const int* in_sizes, int n_in,
                              void* d_out, int out_size, void* d_ws,
                              size_t ws_size, hipStream_t stream) {
  const float* x  = (const float*)d_in[0];
  const float* wq = (const float*)d_in[1];
  const float* bq = (const float*)d_in[2];
  const float* wk = (const float*)d_in[3];
  const float* bk = (const float*)d_in[4];
  const float* wv = (const float*)d_in[5];
  const float* bv = (const float*)d_in[6];
  const float* wg = (const float*)d_in[7];
  const float* bg = (const float*)d_in[8];
  float* out = (float*)d_out;

  short* qt    = (short*)d_ws;                       // [B][N][64]   4 MB
  short* kt    = qt + (size_t)BB * NN * CQ;          // [B][N][64]   4 MB
  short* vt    = kt + (size_t)BB * NN * CQ;          // [B][C][N]   16 MB
  short* wqbf  = vt + (size_t)BB * CC * NN;          // 32 KB
  short* wkbf  = wqbf + (size_t)CQ * CC;             // 32 KB
  short* wvpbf = wkbf + (size_t)CQ * CC;             // 128 KB
  float* bvp   = (float*)(wvpbf + (size_t)CC * CC);  // 1 KB

  prep_kernel<<<dim3(66), 256, 0, stream>>>(wq, wk, wv, wg, bv,
                                            wqbf, wkbf, wvpbf, bvp);
  qkv_kernel<<<dim3(BB, NN / 32), 256, 0, stream>>>(
      x, wqbf, wkbf, wvpbf, bq, bk, bvp, qt, kt, vt);
  attn_kernel<<<dim3(2, NN / 64, BB), 256, 0, stream>>>(qt, kt, vt, bg, out);
}